// Round 9
// baseline (45970.273 us; speedup 1.0000x reference)
//
#include <hip/hip_runtime.h>

#define SEQ 8192
#define H 1024
#define RING 4
#define NB 32          // scan blocks; 16 waves each; 2 units per wave

typedef unsigned long long ull;

// ---------------------------------------------------------------------------
// Projection GEMM (NT): C[i][j] = bias[j] + sum_k A[i][k]*B[j][k]
// (unchanged — not the bottleneck)
// ---------------------------------------------------------------------------
#define KC 32
#define LDT 68

__global__ __launch_bounds__(256) void proj_gemm(
    const float* __restrict__ A,
    const float* __restrict__ B0, const float* __restrict__ b0, float* __restrict__ C0,
    const float* __restrict__ B1, const float* __restrict__ b1, float* __restrict__ C1,
    const float* __restrict__ B2, const float* __restrict__ b2, float* __restrict__ C2)
{
    __shared__ __align__(16) float As[KC * LDT];
    __shared__ __align__(16) float Bs[KC * LDT];

    const float* Bm; const float* bias; float* C;
    if (blockIdx.z == 0)      { Bm = B0; bias = b0; C = C0; }
    else if (blockIdx.z == 1) { Bm = B1; bias = b1; C = C1; }
    else                      { Bm = B2; bias = b2; C = C2; }

    const int j0 = blockIdx.x * 64;
    const int i0 = blockIdx.y * 64;
    const int tid = threadIdx.x;
    const int tx = tid & 15, ty = tid >> 4;
    const int lrow = tid >> 3;
    const int lkq  = tid & 7;

    float acc[4][4];
#pragma unroll
    for (int r = 0; r < 4; r++)
#pragma unroll
        for (int c = 0; c < 4; c++) acc[r][c] = 0.f;

    for (int k0 = 0; k0 < H; k0 += KC) {
#pragma unroll
        for (int half = 0; half < 2; half++) {
            const int row = lrow + half * 32;
            float4 a = *(const float4*)&A[(size_t)(i0 + row) * H + k0 + 4 * lkq];
            As[(4 * lkq + 0) * LDT + row] = a.x;
            As[(4 * lkq + 1) * LDT + row] = a.y;
            As[(4 * lkq + 2) * LDT + row] = a.z;
            As[(4 * lkq + 3) * LDT + row] = a.w;
            float4 b = *(const float4*)&Bm[(size_t)(j0 + row) * H + k0 + 4 * lkq];
            Bs[(4 * lkq + 0) * LDT + row] = b.x;
            Bs[(4 * lkq + 1) * LDT + row] = b.y;
            Bs[(4 * lkq + 2) * LDT + row] = b.z;
            Bs[(4 * lkq + 3) * LDT + row] = b.w;
        }
        __syncthreads();
#pragma unroll
        for (int k = 0; k < KC; k++) {
            float4 a4 = *(const float4*)&As[k * LDT + ty * 4];
            float4 b4 = *(const float4*)&Bs[k * LDT + tx * 4];
            acc[0][0] += a4.x * b4.x; acc[0][1] += a4.x * b4.y;
            acc[0][2] += a4.x * b4.z; acc[0][3] += a4.x * b4.w;
            acc[1][0] += a4.y * b4.x; acc[1][1] += a4.y * b4.y;
            acc[1][2] += a4.y * b4.z; acc[1][3] += a4.y * b4.w;
            acc[2][0] += a4.z * b4.x; acc[2][1] += a4.z * b4.y;
            acc[2][2] += a4.z * b4.z; acc[2][3] += a4.z * b4.w;
            acc[3][0] += a4.w * b4.x; acc[3][1] += a4.w * b4.y;
            acc[3][2] += a4.w * b4.z; acc[3][3] += a4.w * b4.w;
        }
        __syncthreads();
    }

    float4 bi = *(const float4*)&bias[j0 + tx * 4];
#pragma unroll
    for (int r = 0; r < 4; r++) {
        float4 o;
        o.x = acc[r][0] + bi.x; o.y = acc[r][1] + bi.y;
        o.z = acc[r][2] + bi.z; o.w = acc[r][3] + bi.w;
        *(float4*)&C[(size_t)(i0 + ty * 4 + r) * H + j0 + tx * 4] = o;
    }
}

// ---------------------------------------------------------------------------
// GRU scan v7: private-mailbox push. Exchange = tagged 8B (value,step) pairs,
// but each consumer block has a PRIVATE mailbox: mb[c][slot][unit]. After the
// xor-butterfly every lane holds all 6 reduced sums, so each lane computes
// hnew redundantly and lane l pushes unit ua+(l&1) to consumer c=l>>1 — 32
// mailbox copies per wave in ONE store instruction. Every mailbox line has
// exactly 1 reader block + 1 writer wave: no L3 reader/writer queueing (R4's
// shared-ring lines had 64 concurrent reader blocks each — the 3.5k-cycle
// excess). Exact-tag match => poison-safe (0xAA never matches), replay-safe,
// no init. RING=4 (collective gather bounds skew to 1; see proof in journal).
// Double-buffered LDS h => one barrier/step. Rotating block writes outs rows
// coalesced. No XCC_ID, no elections, no inline asm, 32 blocks always fit.
// ---------------------------------------------------------------------------
__global__ __launch_bounds__(1024, 1) void gru_scan(
    const float* __restrict__ xu, const float* __restrict__ xr, const float* __restrict__ xc,
    const float* __restrict__ Wu, const float* __restrict__ Wr, const float* __restrict__ W,
    ull* __restrict__ mb,        // NB*RING*H tagged pairs (no init needed)
    float* __restrict__ out)     // d_out: [H h_final][SEQ*H outputs]
{
    __shared__ float hs[2][H];

    const int bid  = blockIdx.x;    // 0..31
    const int tid  = threadIdx.x;   // 0..1023
    const int wid  = tid >> 6;      // 0..15
    const int lane = tid & 63;
    const int ua   = bid * 32 + wid * 2;   // wave's unit pair
    const int myu  = ua + (lane & 1);      // this lane's unit (32x redundant)

    // register-resident weight rows for units ua, ua+1
    float4 wua[4], wra[4], wca[4], wub[4], wrb[4], wcb[4];
    {
        const float4* pu = (const float4*)(Wu + (size_t)ua * H);
        const float4* pr = (const float4*)(Wr + (size_t)ua * H);
        const float4* pw = (const float4*)(W  + (size_t)ua * H);
#pragma unroll
        for (int m = 0; m < 4; m++) {
            wua[m] = pu[m * 64 + lane];       wub[m] = pu[256 + m * 64 + lane];
            wra[m] = pr[m * 64 + lane];       wrb[m] = pr[256 + m * 64 + lane];
            wca[m] = pw[m * 64 + lane];       wcb[m] = pw[256 + m * 64 + lane];
        }
    }

    float* outs = out + H;
    float hp  = 0.f;                       // prev h of myu (redundant per lane)
    float axu = xu[myu], axr = xr[myu], axc = xc[myu];   // t=0 projections

    for (int t = 0; t < SEQ; t++) {
        float* hcur = hs[t & 1];

        if (t == 0) {
            hcur[tid] = 0.f;
        } else {
            // poll OWN mailbox: wave wid covers units wid*64..+63 (512B, private lines)
            const ull* p = mb + (((size_t)bid * RING + (t & (RING - 1))) << 10)
                              + (wid << 6) + lane;
            ull v = 0;
            bool ok = false;
            for (;;) {
                if (!ok) {
                    v = __hip_atomic_load(p, __ATOMIC_RELAXED, __HIP_MEMORY_SCOPE_SYSTEM);
                    ok = ((int)(v >> 32) == t);
                }
                if (__all(ok)) break;
            }
            hcur[(wid << 6) + lane] = __uint_as_float((unsigned)v);
        }
        __syncthreads();

        const float4* h4 = (const float4*)hcur;
        float sua = 0.f, sra = 0.f, swa = 0.f, sub = 0.f, srb = 0.f, swb = 0.f;
#pragma unroll
        for (int m = 0; m < 4; m++) {
            float4 h = h4[m * 64 + lane];
            sua += wua[m].x * h.x + wua[m].y * h.y + wua[m].z * h.z + wua[m].w * h.w;
            sra += wra[m].x * h.x + wra[m].y * h.y + wra[m].z * h.z + wra[m].w * h.w;
            swa += wca[m].x * h.x + wca[m].y * h.y + wca[m].z * h.z + wca[m].w * h.w;
            sub += wub[m].x * h.x + wub[m].y * h.y + wub[m].z * h.z + wub[m].w * h.w;
            srb += wrb[m].x * h.x + wrb[m].y * h.y + wrb[m].z * h.z + wrb[m].w * h.w;
            swb += wcb[m].x * h.x + wcb[m].y * h.y + wcb[m].z * h.z + wcb[m].w * h.w;
        }
#pragma unroll
        for (int off = 32; off > 0; off >>= 1) {
            sua += __shfl_xor(sua, off, 64);
            sra += __shfl_xor(sra, off, 64);
            swa += __shfl_xor(swa, off, 64);
            sub += __shfl_xor(sub, off, 64);
            srb += __shfl_xor(srb, off, 64);
            swb += __shfl_xor(swb, off, 64);
        }

        // every lane: gates for its unit (identical across the 32 lane-copies)
        {
            float su = (lane & 1) ? sub : sua;
            float sr = (lane & 1) ? srb : sra;
            float sw = (lane & 1) ? swb : swa;
            float u    = 1.f / (1.f + __expf(-(axu + su)));
            float r    = 1.f / (1.f + __expf(-(axr + sr)));
            float cand = 1.f / (1.f + __expf(-(axc + r * sw)));
            float hnew = u * hp + (1.f - u) * cand;
            hp = hnew;
            // push to consumer (lane>>1)'s private mailbox — 1 store per lane
            ull pkt = ((ull)(unsigned)(t + 1) << 32) | (ull)__float_as_uint(hnew);
            ull* q = mb + (((size_t)(lane >> 1) * RING + ((t + 1) & (RING - 1))) << 10)
                        + myu;
            __hip_atomic_store(q, pkt, __ATOMIC_RELAXED, __HIP_MEMORY_SCOPE_SYSTEM);
        }

        // rotating writer: coalesced outs row t-1 (hcur = h after step t-1)
        if (t > 0 && bid == (t & (NB - 1)))
            outs[(size_t)(t - 1) * H + tid] = hcur[tid];

        // prefetch next step's projections (hidden under next poll)
        if (t + 1 < SEQ) {
            axu = xu[(size_t)(t + 1) * H + myu];
            axr = xr[(size_t)(t + 1) * H + myu];
            axc = xc[(size_t)(t + 1) * H + myu];
        }
        // no second barrier: hs double-buffered, next fill uses the other half
    }

    if (bid == 0) {
        // gather tag SEQ from own mailbox: outs row SEQ-1 and h_final
        const ull* p = mb + (((size_t)0 * RING + (SEQ & (RING - 1))) << 10)
                          + (wid << 6) + lane;
        ull v = 0;
        bool ok = false;
        for (;;) {
            if (!ok) {
                v = __hip_atomic_load(p, __ATOMIC_RELAXED, __HIP_MEMORY_SCOPE_SYSTEM);
                ok = ((int)(v >> 32) == SEQ);
            }
            if (__all(ok)) break;
        }
        float hv = __uint_as_float((unsigned)v);
        outs[(size_t)(SEQ - 1) * H + (wid << 6) + lane] = hv;
        out[(wid << 6) + lane] = hv;
    }
}

// ---------------------------------------------------------------------------
extern "C" void kernel_launch(void* const* d_in, const int* in_sizes, int n_in,
                              void* d_out, int out_size, void* d_ws, size_t ws_size,
                              hipStream_t stream) {
    const float* x  = (const float*)d_in[0];
    const float* Uu = (const float*)d_in[1];
    const float* Wu = (const float*)d_in[2];
    const float* Bu = (const float*)d_in[3];
    const float* Ur = (const float*)d_in[4];
    const float* Wr = (const float*)d_in[5];
    const float* Br = (const float*)d_in[6];
    const float* U  = (const float*)d_in[7];
    const float* W  = (const float*)d_in[8];
    const float* B  = (const float*)d_in[9];

    char* ws = (char*)d_ws;
    const size_t MAT = (size_t)SEQ * H * sizeof(float);     // 32 MB
    float* xu = (float*)(ws);
    float* xr = (float*)(ws + MAT);
    float* xc = (float*)(ws + 2 * MAT);
    ull*   mb = (ull*)(ws + 3 * MAT);                       // 1 MB mailboxes (no init)

    dim3 g(H / 64, SEQ / 64, 3);
    proj_gemm<<<g, 256, 0, stream>>>(x, Uu, Bu, xu, Ur, Br, xr, U, B, xc);

    gru_scan<<<NB, 1024, 0, stream>>>(xu, xr, xc, Wu, Wr, W, mb, (float*)d_out);
}

// Round 10
// 43019.946 us; speedup vs baseline: 1.0686x; 1.0686x over previous
//
#include <hip/hip_runtime.h>

#define SEQ 8192
#define H 1024
#define RING 4
#define NWAVE 512      // independent scan waves; 2 units each

typedef unsigned long long ull;
typedef unsigned int v4u __attribute__((ext_vector_type(4)));

// ---------------------------------------------------------------------------
// Projection GEMM (NT): C[i][j] = bias[j] + sum_k A[i][k]*B[j][k]
// (unchanged — not the bottleneck)
// ---------------------------------------------------------------------------
#define KC 32
#define LDT 68

__global__ __launch_bounds__(256) void proj_gemm(
    const float* __restrict__ A,
    const float* __restrict__ B0, const float* __restrict__ b0, float* __restrict__ C0,
    const float* __restrict__ B1, const float* __restrict__ b1, float* __restrict__ C1,
    const float* __restrict__ B2, const float* __restrict__ b2, float* __restrict__ C2)
{
    __shared__ __align__(16) float As[KC * LDT];
    __shared__ __align__(16) float Bs[KC * LDT];

    const float* Bm; const float* bias; float* C;
    if (blockIdx.z == 0)      { Bm = B0; bias = b0; C = C0; }
    else if (blockIdx.z == 1) { Bm = B1; bias = b1; C = C1; }
    else                      { Bm = B2; bias = b2; C = C2; }

    const int j0 = blockIdx.x * 64;
    const int i0 = blockIdx.y * 64;
    const int tid = threadIdx.x;
    const int tx = tid & 15, ty = tid >> 4;
    const int lrow = tid >> 3;
    const int lkq  = tid & 7;

    float acc[4][4];
#pragma unroll
    for (int r = 0; r < 4; r++)
#pragma unroll
        for (int c = 0; c < 4; c++) acc[r][c] = 0.f;

    for (int k0 = 0; k0 < H; k0 += KC) {
#pragma unroll
        for (int half = 0; half < 2; half++) {
            const int row = lrow + half * 32;
            float4 a = *(const float4*)&A[(size_t)(i0 + row) * H + k0 + 4 * lkq];
            As[(4 * lkq + 0) * LDT + row] = a.x;
            As[(4 * lkq + 1) * LDT + row] = a.y;
            As[(4 * lkq + 2) * LDT + row] = a.z;
            As[(4 * lkq + 3) * LDT + row] = a.w;
            float4 b = *(const float4*)&Bm[(size_t)(j0 + row) * H + k0 + 4 * lkq];
            Bs[(4 * lkq + 0) * LDT + row] = b.x;
            Bs[(4 * lkq + 1) * LDT + row] = b.y;
            Bs[(4 * lkq + 2) * LDT + row] = b.z;
            Bs[(4 * lkq + 3) * LDT + row] = b.w;
        }
        __syncthreads();
#pragma unroll
        for (int k = 0; k < KC; k++) {
            float4 a4 = *(const float4*)&As[k * LDT + ty * 4];
            float4 b4 = *(const float4*)&Bs[k * LDT + tx * 4];
            acc[0][0] += a4.x * b4.x; acc[0][1] += a4.x * b4.y;
            acc[0][2] += a4.x * b4.z; acc[0][3] += a4.x * b4.w;
            acc[1][0] += a4.y * b4.x; acc[1][1] += a4.y * b4.y;
            acc[1][2] += a4.y * b4.z; acc[1][3] += a4.y * b4.w;
            acc[2][0] += a4.z * b4.x; acc[2][1] += a4.z * b4.y;
            acc[2][2] += a4.z * b4.z; acc[2][3] += a4.z * b4.w;
            acc[3][0] += a4.w * b4.x; acc[3][1] += a4.w * b4.y;
            acc[3][2] += a4.w * b4.z; acc[3][3] += a4.w * b4.w;
        }
        __syncthreads();
    }

    float4 bi = *(const float4*)&bias[j0 + tx * 4];
#pragma unroll
    for (int r = 0; r < 4; r++) {
        float4 o;
        o.x = acc[r][0] + bi.x; o.y = acc[r][1] + bi.y;
        o.z = acc[r][2] + bi.z; o.w = acc[r][3] + bi.w;
        *(float4*)&C[(size_t)(i0 + ty * 4 + r) * H + j0 + tx * 4] = o;
    }
}

// ---------------------------------------------------------------------------
// GRU scan v8: barrier-free waves. 512 independent waves, 2 units each.
// Per step each wave fetches the FULL tagged h-vector (8 dwordx4/lane, all
// concurrently in flight), FMAs straight from the loaded registers (values in
// even dwords, tags in odd), butterflies 6 sums, computes gates redundantly
// in all lanes, lane0 publishes one 16B tagged packet. No __syncthreads, no
// LDS staging, no per-wave straggler max. Retries reload only the failing
// registers (exec-masked). Rotating wave (t mod 512) writes outs row t-1
// through its private LDS strip AFTER publishing. Ring slot = t mod 4,
// exact-tag match (memset to 0 at launch; tags are 1..8192 — stale/poison
// never matches).
// ---------------------------------------------------------------------------
#define RELOAD(i, P, OFFSTR)                                                  \
    if (!ok[i]) {                                                             \
        asm volatile("global_load_dwordx4 %0, %1, off" OFFSTR " sc0 sc1"      \
                     : "=&v"(x[i]) : "v"(P) : "memory");                      \
    }

__global__ __launch_bounds__(512, 1) void gru_scan(
    const float* __restrict__ xu, const float* __restrict__ xr, const float* __restrict__ xc,
    const float* __restrict__ Wu, const float* __restrict__ Wr, const float* __restrict__ W,
    ull* __restrict__ th,        // RING*H tagged pairs (memset 0 at launch)
    float* __restrict__ out)     // d_out: [H h_final][SEQ*H outputs]
{
    __shared__ float rowbuf[8][H];   // per-wave private strip for outs routing

    const int tid  = threadIdx.x;
    const int wid  = tid >> 6;            // 0..7
    const int lane = tid & 63;
    const int gw   = blockIdx.x * 8 + wid;  // 0..511
    const int ua   = gw * 2;              // this wave's unit pair

    // weights: wt[gate][unit][batch] — lane covers k = batch*128 + 2*lane, +1
    float2 wt[3][2][8];
    {
        const float* base[3] = { Wu, Wr, W };
#pragma unroll
        for (int g = 0; g < 3; g++)
#pragma unroll
            for (int u = 0; u < 2; u++) {
                const float* row = base[g] + (size_t)(ua + u) * H + 2 * lane;
#pragma unroll
                for (int i = 0; i < 8; i++)
                    wt[g][u][i] = *(const float2*)(row + i * 128);
            }
    }

    float* outs = out + H;
    float hpa = 0.f, hpb = 0.f;          // prev h (redundant in all lanes)

    for (int t = 0; t < SEQ; t++) {
        float2 axu = *(const float2*)(xu + (size_t)t * H + ua);
        float2 axr = *(const float2*)(xr + (size_t)t * H + ua);
        float2 axc = *(const float2*)(xc + (size_t)t * H + ua);

        v4u x[8];
        float sua = 0.f, sra = 0.f, swa = 0.f, sub = 0.f, srb = 0.f, swb = 0.f;

        if (t > 0) {
            const char* p0 = (const char*)(th + ((size_t)(t & (RING - 1)) << 10)) + lane * 16;
            const char* p1 = p0 + 4096;
            // fetch all 1024 tagged pairs: 8 concurrent dwordx4 per lane
            asm volatile(
                "global_load_dwordx4 %0, %8, off sc0 sc1\n\t"
                "global_load_dwordx4 %1, %8, off offset:1024 sc0 sc1\n\t"
                "global_load_dwordx4 %2, %8, off offset:2048 sc0 sc1\n\t"
                "global_load_dwordx4 %3, %8, off offset:3072 sc0 sc1\n\t"
                "global_load_dwordx4 %4, %9, off sc0 sc1\n\t"
                "global_load_dwordx4 %5, %9, off offset:1024 sc0 sc1\n\t"
                "global_load_dwordx4 %6, %9, off offset:2048 sc0 sc1\n\t"
                "global_load_dwordx4 %7, %9, off offset:3072 sc0 sc1\n\t"
                "s_waitcnt vmcnt(0)"
                : "=&v"(x[0]), "=&v"(x[1]), "=&v"(x[2]), "=&v"(x[3]),
                  "=&v"(x[4]), "=&v"(x[5]), "=&v"(x[6]), "=&v"(x[7])
                : "v"(p0), "v"(p1)
                : "memory");

            bool ok[8];
#pragma unroll
            for (int i = 0; i < 8; i++)
                ok[i] = ((int)x[i].y == t) && ((int)x[i].w == t);

            for (;;) {
                bool all8 = ok[0] && ok[1] && ok[2] && ok[3] &&
                            ok[4] && ok[5] && ok[6] && ok[7];
                if (__all(all8)) break;
                // reload only failing registers (exec-masked per register)
                RELOAD(0, p0, "")
                RELOAD(1, p0, " offset:1024")
                RELOAD(2, p0, " offset:2048")
                RELOAD(3, p0, " offset:3072")
                RELOAD(4, p1, "")
                RELOAD(5, p1, " offset:1024")
                RELOAD(6, p1, " offset:2048")
                RELOAD(7, p1, " offset:3072")
                asm volatile("s_waitcnt vmcnt(0)"
                             : "+v"(x[0]), "+v"(x[1]), "+v"(x[2]), "+v"(x[3]),
                               "+v"(x[4]), "+v"(x[5]), "+v"(x[6]), "+v"(x[7])
                             : : "memory");
#pragma unroll
                for (int i = 0; i < 8; i++)
                    if (!ok[i]) ok[i] = ((int)x[i].y == t) && ((int)x[i].w == t);
            }

            // dot products straight from the poll registers
#pragma unroll
            for (int i = 0; i < 8; i++) {
                float h0 = __uint_as_float(x[i].x);
                float h1 = __uint_as_float(x[i].z);
                sua += wt[0][0][i].x * h0 + wt[0][0][i].y * h1;
                sra += wt[1][0][i].x * h0 + wt[1][0][i].y * h1;
                swa += wt[2][0][i].x * h0 + wt[2][0][i].y * h1;
                sub += wt[0][1][i].x * h0 + wt[0][1][i].y * h1;
                srb += wt[1][1][i].x * h0 + wt[1][1][i].y * h1;
                swb += wt[2][1][i].x * h0 + wt[2][1][i].y * h1;
            }
#pragma unroll
            for (int off = 32; off > 0; off >>= 1) {
                sua += __shfl_xor(sua, off, 64);
                sra += __shfl_xor(sra, off, 64);
                swa += __shfl_xor(swa, off, 64);
                sub += __shfl_xor(sub, off, 64);
                srb += __shfl_xor(srb, off, 64);
                swb += __shfl_xor(swb, off, 64);
            }
        }

        // gates (identical in all 64 lanes)
        float u_a = 1.f / (1.f + __expf(-(axu.x + sua)));
        float r_a = 1.f / (1.f + __expf(-(axr.x + sra)));
        float c_a = 1.f / (1.f + __expf(-(axc.x + r_a * swa)));
        float hna = u_a * hpa + (1.f - u_a) * c_a;
        float u_b = 1.f / (1.f + __expf(-(axu.y + sub)));
        float r_b = 1.f / (1.f + __expf(-(axr.y + srb)));
        float c_b = 1.f / (1.f + __expf(-(axc.y + r_b * swb)));
        float hnb = u_b * hpb + (1.f - u_b) * c_b;
        hpa = hna; hpb = hnb;

        // publish: ONE 16B tagged packet from lane 0
        if (lane == 0) {
            v4u pkt;
            pkt.x = __float_as_uint(hna); pkt.y = (unsigned)(t + 1);
            pkt.z = __float_as_uint(hnb); pkt.w = (unsigned)(t + 1);
            ull* q = th + (((size_t)((t + 1) & (RING - 1))) << 10) + ua;
            asm volatile("global_store_dwordx4 %0, %1, off sc0 sc1"
                         :: "v"(q), "v"(pkt) : "memory");
        }

        // rotating outs writer: wave (t mod 512) holds h_t in x[] — write row t-1
        if (t > 0 && gw == (t & (NWAVE - 1))) {
#pragma unroll
            for (int i = 0; i < 8; i++) {
                rowbuf[wid][i * 128 + 2 * lane]     = __uint_as_float(x[i].x);
                rowbuf[wid][i * 128 + 2 * lane + 1] = __uint_as_float(x[i].z);
            }
            float* dst = outs + (size_t)(t - 1) * H;
#pragma unroll
            for (int q = 0; q < 4; q++)
                *(float4*)&dst[q * 256 + lane * 4] =
                    *(const float4*)&rowbuf[wid][q * 256 + lane * 4];
        }
    }

    // wave 0: gather tag SEQ -> outs row SEQ-1 and h_final
    if (gw == 0) {
        const char* p0 = (const char*)th + lane * 16;   // slot 8192&3 == 0
        const char* p1 = p0 + 4096;
        v4u x[8];
        asm volatile(
            "global_load_dwordx4 %0, %8, off sc0 sc1\n\t"
            "global_load_dwordx4 %1, %8, off offset:1024 sc0 sc1\n\t"
            "global_load_dwordx4 %2, %8, off offset:2048 sc0 sc1\n\t"
            "global_load_dwordx4 %3, %8, off offset:3072 sc0 sc1\n\t"
            "global_load_dwordx4 %4, %9, off sc0 sc1\n\t"
            "global_load_dwordx4 %5, %9, off offset:1024 sc0 sc1\n\t"
            "global_load_dwordx4 %6, %9, off offset:2048 sc0 sc1\n\t"
            "global_load_dwordx4 %7, %9, off offset:3072 sc0 sc1\n\t"
            "s_waitcnt vmcnt(0)"
            : "=&v"(x[0]), "=&v"(x[1]), "=&v"(x[2]), "=&v"(x[3]),
              "=&v"(x[4]), "=&v"(x[5]), "=&v"(x[6]), "=&v"(x[7])
            : "v"(p0), "v"(p1)
            : "memory");
        bool ok[8];
#pragma unroll
        for (int i = 0; i < 8; i++)
            ok[i] = ((int)x[i].y == SEQ) && ((int)x[i].w == SEQ);
        for (;;) {
            bool all8 = ok[0] && ok[1] && ok[2] && ok[3] &&
                        ok[4] && ok[5] && ok[6] && ok[7];
            if (__all(all8)) break;
            RELOAD(0, p0, "")
            RELOAD(1, p0, " offset:1024")
            RELOAD(2, p0, " offset:2048")
            RELOAD(3, p0, " offset:3072")
            RELOAD(4, p1, "")
            RELOAD(5, p1, " offset:1024")
            RELOAD(6, p1, " offset:2048")
            RELOAD(7, p1, " offset:3072")
            asm volatile("s_waitcnt vmcnt(0)"
                         : "+v"(x[0]), "+v"(x[1]), "+v"(x[2]), "+v"(x[3]),
                           "+v"(x[4]), "+v"(x[5]), "+v"(x[6]), "+v"(x[7])
                         : : "memory");
#pragma unroll
            for (int i = 0; i < 8; i++)
                if (!ok[i]) ok[i] = ((int)x[i].y == SEQ) && ((int)x[i].w == SEQ);
        }
#pragma unroll
        for (int i = 0; i < 8; i++) {
            rowbuf[0][i * 128 + 2 * lane]     = __uint_as_float(x[i].x);
            rowbuf[0][i * 128 + 2 * lane + 1] = __uint_as_float(x[i].z);
        }
        float* dst = outs + (size_t)(SEQ - 1) * H;
#pragma unroll
        for (int q = 0; q < 4; q++) {
            float4 v = *(const float4*)&rowbuf[0][q * 256 + lane * 4];
            *(float4*)&dst[q * 256 + lane * 4] = v;
            *(float4*)&out[q * 256 + lane * 4] = v;
        }
    }
}

// ---------------------------------------------------------------------------
extern "C" void kernel_launch(void* const* d_in, const int* in_sizes, int n_in,
                              void* d_out, int out_size, void* d_ws, size_t ws_size,
                              hipStream_t stream) {
    const float* x  = (const float*)d_in[0];
    const float* Uu = (const float*)d_in[1];
    const float* Wu = (const float*)d_in[2];
    const float* Bu = (const float*)d_in[3];
    const float* Ur = (const float*)d_in[4];
    const float* Wr = (const float*)d_in[5];
    const float* Br = (const float*)d_in[6];
    const float* U  = (const float*)d_in[7];
    const float* W  = (const float*)d_in[8];
    const float* B  = (const float*)d_in[9];

    char* ws = (char*)d_ws;
    const size_t MAT = (size_t)SEQ * H * sizeof(float);     // 32 MB
    float* xu = (float*)(ws);
    float* xr = (float*)(ws + MAT);
    float* xc = (float*)(ws + 2 * MAT);
    ull*   th = (ull*)(ws + 3 * MAT);                       // 32 KB ring

    hipMemsetAsync(th, 0, (size_t)RING * H * sizeof(ull), stream);

    dim3 g(H / 64, SEQ / 64, 3);
    proj_gemm<<<g, 256, 0, stream>>>(x, Uu, Bu, xu, Ur, Br, xr, U, B, xc);

    gru_scan<<<NWAVE / 8, 512, 0, stream>>>(xu, xr, xc, Wu, Wr, W, th, (float*)d_out);
}